// Round 15
// baseline (56.542 us; speedup 1.0000x reference)
//
#include <hip/hip_runtime.h>
#include <hip/hip_bf16.h>

#define BATCH   16384
#define NTAGS   1024
#define DIM     64
#define HID     128
#define REPT    8          // tail (phases 2+3) repeat for profiling; idempotent

typedef __attribute__((ext_vector_type(8))) short bf16x8;
typedef __attribute__((ext_vector_type(4))) float f32x4;

__device__ __forceinline__ unsigned short f2bf(float v) {
    unsigned u = __builtin_bit_cast(unsigned, v);
    return (unsigned short)((u + 0x7FFFu + ((u >> 16) & 1u)) >> 16);   // RNE
}

// ---------------------------------------------------------------------------
// prep (R3-verified): pack S_emb and Wfc[0:192] into bf16 16x16x32
// B-fragment-linear layouts (col = lane&15, k = (lane>>4)*8 + j).
// ---------------------------------------------------------------------------
__global__ __launch_bounds__(256) void prep_pack(const float* __restrict__ S,
                                                 const float* __restrict__ Wfc,
                                                 unsigned short* __restrict__ Spack,
                                                 unsigned short* __restrict__ Wp)
{
    int tid = blockIdx.x * 256 + threadIdx.x;   // 0..90111
    if (tid < 65536) {
        int j = tid & 7, l = (tid >> 3) & 63, nf = (tid >> 9) & 3, ks = tid >> 11;
        int k = ks * 32 + (l >> 4) * 8 + j;
        int d = nf * 16 + (l & 15);
        Spack[tid] = f2bf(S[k * 64 + d]);
    } else if (tid < 65536 + 24576) {
        int t2 = tid - 65536;                   // 0..24575
        int j = t2 & 7, l = (t2 >> 3) & 63, ct = (t2 >> 9) & 7, kt = t2 >> 12;
        int k = kt * 32 + (l >> 4) * 8 + j;     // 0..191
        int col = ct * 16 + (l & 15);
        Wp[t2] = f2bf(Wfc[k * 128 + col]);
    }
}

// ---------------------------------------------------------------------------
// fused (R3 structure, int-add counts), with phases 2+3 repeated REPT times.
// Each pass recomputes and re-stores identical values (idempotent), so the
// output is bit-identical to the REPT=1 kernel; duration isolates tail cost.
// ---------------------------------------------------------------------------
__global__ __launch_bounds__(256) void fused_kernel(
    const int* __restrict__ questions, const int* __restrict__ T,
    const float* __restrict__ dfeat, const float* __restrict__ Qemb,
    const float* __restrict__ Wdiff, const float* __restrict__ bdiff,
    const float* __restrict__ Wfc, const float* __restrict__ bfc,
    const float* __restrict__ Wout, const float* __restrict__ bout,
    const unsigned short* __restrict__ Spack, const unsigned short* __restrict__ Wp,
    float* __restrict__ out_e, float* __restrict__ out_p)
{
    __shared__ alignas(16) float accred[4][16][68];
    __shared__ float cntred[4][16];
    __shared__ alignas(16) unsigned short zb[16][200];
    __shared__ float scal[16][3];
    __shared__ float pacc[16][4];

    const int tid  = threadIdx.x;
    const int lane = tid & 63;
    const int wid  = tid >> 6;
    const int g    = lane >> 4;
    const int rl   = lane & 15;
    const int rb   = blockIdx.x * 16;

    // ---- phase 1: T @ S over this wave's K-quarter --------------------------
    f32x4 a0{}, a1{}, a2{}, a3{};
    int c = 0;
    {
        const int* tp = T + (size_t)(rb + rl) * 1024 + wid * 256 + g * 8;
        const unsigned short* sp = Spack + (size_t)wid * 8 * 2048 + lane * 8;

#pragma unroll
        for (int ks = 0; ks < 8; ++ks) {
            int4 t0 = *(const int4*)(tp + ks * 32);
            int4 t1 = *(const int4*)(tp + ks * 32 + 4);
            c += t0.x + t0.y + t0.z + t0.w + t1.x + t1.y + t1.z + t1.w;
            bf16x8 af;
            af[0] = (short)((-t0.x) & 0x3F80);
            af[1] = (short)((-t0.y) & 0x3F80);
            af[2] = (short)((-t0.z) & 0x3F80);
            af[3] = (short)((-t0.w) & 0x3F80);
            af[4] = (short)((-t1.x) & 0x3F80);
            af[5] = (short)((-t1.y) & 0x3F80);
            af[6] = (short)((-t1.z) & 0x3F80);
            af[7] = (short)((-t1.w) & 0x3F80);

            const unsigned short* s2 = sp + ks * 2048;
            bf16x8 b0 = *(const bf16x8*)(s2);
            bf16x8 b1 = *(const bf16x8*)(s2 + 512);
            bf16x8 b2 = *(const bf16x8*)(s2 + 1024);
            bf16x8 b3 = *(const bf16x8*)(s2 + 1536);

            a0 = __builtin_amdgcn_mfma_f32_16x16x32_bf16(af, b0, a0, 0, 0, 0);
            a1 = __builtin_amdgcn_mfma_f32_16x16x32_bf16(af, b1, a1, 0, 0, 0);
            a2 = __builtin_amdgcn_mfma_f32_16x16x32_bf16(af, b2, a2, 0, 0, 0);
            a3 = __builtin_amdgcn_mfma_f32_16x16x32_bf16(af, b3, a3, 0, 0, 0);
        }
    }
    c += __shfl_xor(c, 16);
    c += __shfl_xor(c, 32);
    if (lane < 16) cntred[wid][lane] = (float)c;

#pragma unroll
    for (int r = 0; r < 4; ++r) {
        int row = g * 4 + r;
        accred[wid][row][rl]      = a0[r];
        accred[wid][row][16 + rl] = a1[r];
        accred[wid][row][32 + rl] = a2[r];
        accred[wid][row][48 + rl] = a3[r];
    }
    __syncthreads();

    // ==== TAIL (phases 2+3), repeated REPT times for measurement =============
    for (int rt = 0; rt < REPT; ++rt) {
        asm volatile("" ::: "memory");    // forbid cross-pass CSE

        // ---- phase 2: combine partials, build z (bf16) ----------------------
        {
            int r = tid >> 4, c16 = tid & 15, d0 = c16 * 4;
            float cc = cntred[0][r] + cntred[1][r] + cntred[2][r] + cntred[3][r];
            float inv = 1.f / cc;
            float4 m0 = *(const float4*)&accred[0][r][d0];
            float4 m1 = *(const float4*)&accred[1][r][d0];
            float4 m2 = *(const float4*)&accred[2][r][d0];
            float4 m3 = *(const float4*)&accred[3][r][d0];
            float mu[4];
            mu[0] = (m0.x + m1.x + m2.x + m3.x) * inv;
            mu[1] = (m0.y + m1.y + m2.y + m3.y) * inv;
            mu[2] = (m0.z + m1.z + m2.z + m3.z) * inv;
            mu[3] = (m0.w + m1.w + m2.w + m3.w) * inv;

            int qi = questions[rb + r];
            float4 q4 = *(const float4*)(Qemb + (size_t)qi * 64 + d0);
            float q[4] = {q4.x, q4.y, q4.z, q4.w};

            float f0 = dfeat[(rb + r) * 3 + 0];
            float f1 = dfeat[(rb + r) * 3 + 1];
            float f2 = dfeat[(rb + r) * 3 + 2];
            float aa[4];
#pragma unroll
            for (int d = 0; d < 4; ++d)
                aa[d] = bdiff[d0 + d] + f0 * Wdiff[d0 + d] + f1 * Wdiff[64 + d0 + d]
                      + f2 * Wdiff[128 + d0 + d];

            ushort4 qv, mv, av;
            qv.x = f2bf(q[0]);  qv.y = f2bf(q[1]);  qv.z = f2bf(q[2]);  qv.w = f2bf(q[3]);
            mv.x = f2bf(mu[0]); mv.y = f2bf(mu[1]); mv.z = f2bf(mu[2]); mv.w = f2bf(mu[3]);
            av.x = f2bf(aa[0]); av.y = f2bf(aa[1]); av.z = f2bf(aa[2]); av.w = f2bf(aa[3]);
            *(ushort4*)&zb[r][d0]       = qv;
            *(ushort4*)&zb[r][64 + d0]  = mv;
            *(ushort4*)&zb[r][128 + d0] = av;

            float s12 = 0.f, s13 = 0.f, s23 = 0.f;
#pragma unroll
            for (int d = 0; d < 4; ++d) {
                s12 += q[d] * mu[d];
                s13 += q[d] * aa[d];
                s23 += mu[d] * aa[d];
            }
#pragma unroll
            for (int off = 1; off < 16; off <<= 1) {
                s12 += __shfl_xor(s12, off);
                s13 += __shfl_xor(s13, off);
                s23 += __shfl_xor(s23, off);
            }
            if (c16 == 0) { scal[r][0] = s12; scal[r][1] = s13; scal[r][2] = s23; }
        }
        __syncthreads();

        // ---- phase 3: tail GEMM (K=192) + epilogue --------------------------
        {
            bf16x8 afr[6];
#pragma unroll
            for (int kt = 0; kt < 6; ++kt)
                afr[kt] = *(const bf16x8*)&zb[rl][kt * 32 + g * 8];

            float pr0 = 0.f, pr1 = 0.f, pr2 = 0.f, pr3 = 0.f;
#pragma unroll
            for (int c2 = 0; c2 < 2; ++c2) {
                int ct = wid * 2 + c2;
                f32x4 e{};
                const unsigned short* wp = Wp + (size_t)ct * 512 + lane * 8;
#pragma unroll
                for (int kt = 0; kt < 6; ++kt) {
                    bf16x8 bfr = *(const bf16x8*)(wp + (size_t)kt * 4096);
                    e = __builtin_amdgcn_mfma_f32_16x16x32_bf16(afr[kt], bfr, e, 0, 0, 0);
                }
                int h = ct * 16 + rl;
                float w192 = Wfc[192 * 128 + h];
                float w193 = Wfc[193 * 128 + h];
                float w194 = Wfc[194 * 128 + h];
                float bb = bfc[h];
                float wo = Wout[h];
#pragma unroll
                for (int r = 0; r < 4; ++r) {
                    int row = g * 4 + r;
                    float ev = e[r] + bb + scal[row][0] * w192 + scal[row][1] * w193
                             + scal[row][2] * w194;
                    ev = ev > 0.f ? ev : 0.f;
                    out_e[(size_t)(rb + row) * 128 + h] = ev;
                    float pc = ev * wo;
                    if (r == 0) pr0 += pc; else if (r == 1) pr1 += pc;
                    else if (r == 2) pr2 += pc; else pr3 += pc;
                }
            }
#pragma unroll
            for (int off = 1; off < 16; off <<= 1) {
                pr0 += __shfl_xor(pr0, off);
                pr1 += __shfl_xor(pr1, off);
                pr2 += __shfl_xor(pr2, off);
                pr3 += __shfl_xor(pr3, off);
            }
            if (rl == 0) {
                pacc[g * 4 + 0][wid] = pr0;
                pacc[g * 4 + 1][wid] = pr1;
                pacc[g * 4 + 2][wid] = pr2;
                pacc[g * 4 + 3][wid] = pr3;
            }
        }
        __syncthreads();
        if (tid < 16) {
            float v = pacc[tid][0] + pacc[tid][1] + pacc[tid][2] + pacc[tid][3] + bout[0];
            out_p[rb + tid] = 1.f / (1.f + expf(-v));
        }
        __syncthreads();
    }
}

// ---------------------------------------------------------------------------
extern "C" void kernel_launch(void* const* d_in, const int* in_sizes, int n_in,
                              void* d_out, int out_size, void* d_ws, size_t ws_size,
                              hipStream_t stream)
{
    const int*   questions = (const int*)d_in[0];
    const int*   T         = (const int*)d_in[1];
    const float* dfeat     = (const float*)d_in[2];
    const float* Qemb      = (const float*)d_in[3];
    const float* Semb      = (const float*)d_in[4];
    const float* Wdiff     = (const float*)d_in[5];
    const float* bdiff     = (const float*)d_in[6];
    const float* Wfc       = (const float*)d_in[7];
    const float* bfc       = (const float*)d_in[8];
    const float* Wout      = (const float*)d_in[9];
    const float* bout      = (const float*)d_in[10];

    char* ws = (char*)d_ws;
    unsigned short* Spack = (unsigned short*)ws;             // 128 KiB
    unsigned short* Wp    = (unsigned short*)(ws + 131072);  // 48 KiB

    float* out_e = (float*)d_out;
    float* out_p = out_e + (size_t)BATCH * HID;

    hipLaunchKernelGGL(prep_pack, dim3(352), dim3(256), 0, stream, Semb, Wfc, Spack, Wp);
    hipLaunchKernelGGL(fused_kernel, dim3(BATCH / 16), dim3(256), 0, stream,
                       questions, T, dfeat, Qemb, Wdiff, bdiff, Wfc, bfc, Wout, bout,
                       Spack, Wp, out_e, out_p);
}

// Round 16
// 32.331 us; speedup vs baseline: 1.7488x; 1.7488x over previous
//
#include <hip/hip_runtime.h>
#include <hip/hip_bf16.h>

#define BATCH   16384
#define NTAGS   1024
#define DIM     64
#define HID     128

typedef __attribute__((ext_vector_type(8))) short bf16x8;
typedef __attribute__((ext_vector_type(4))) float f32x4;

__device__ __forceinline__ unsigned short f2bf(float v) {
    unsigned u = __builtin_bit_cast(unsigned, v);
    return (unsigned short)((u + 0x7FFFu + ((u >> 16) & 1u)) >> 16);   // RNE
}
__device__ __forceinline__ float bf2f(unsigned short u) {
    return __builtin_bit_cast(float, ((unsigned)u) << 16);
}
__device__ __forceinline__ bf16x8 mk_af(int4 u, int4 v) {
    bf16x8 af;
    af[0] = (short)((-u.x) & 0x3F80);
    af[1] = (short)((-u.y) & 0x3F80);
    af[2] = (short)((-u.z) & 0x3F80);
    af[3] = (short)((-u.w) & 0x3F80);
    af[4] = (short)((-v.x) & 0x3F80);
    af[5] = (short)((-v.y) & 0x3F80);
    af[6] = (short)((-v.z) & 0x3F80);
    af[7] = (short)((-v.w) & 0x3F80);
    return af;
}

// ---------------------------------------------------------------------------
// prep (R3-verified): pack S_emb and Wfc[0:192] into bf16 16x16x32
// B-fragment-linear layouts (col = lane&15, k = (lane>>4)*8 + j).
// ---------------------------------------------------------------------------
__global__ __launch_bounds__(256) void prep_pack(const float* __restrict__ S,
                                                 const float* __restrict__ Wfc,
                                                 unsigned short* __restrict__ Spack,
                                                 unsigned short* __restrict__ Wp)
{
    int tid = blockIdx.x * 256 + threadIdx.x;   // 0..90111
    if (tid < 65536) {
        int j = tid & 7, l = (tid >> 3) & 63, nf = (tid >> 9) & 3, ks = tid >> 11;
        int k = ks * 32 + (l >> 4) * 8 + j;
        int d = nf * 16 + (l & 15);
        Spack[tid] = f2bf(S[k * 64 + d]);
    } else if (tid < 65536 + 24576) {
        int t2 = tid - 65536;                   // 0..24575
        int j = t2 & 7, l = (t2 >> 3) & 63, ct = (t2 >> 9) & 7, kt = t2 >> 12;
        int k = kt * 32 + (l >> 4) * 8 + j;     // 0..191
        int col = ct * 16 + (l & 15);
        Wp[t2] = f2bf(Wfc[k * 128 + col]);
    }
}

// ---------------------------------------------------------------------------
// mega2: R8 barrier-free structure (wave owns 16 rows end-to-end, zero
// __syncthreads) + DEEP REGISTER PIPELINING in phase A:
//   - T double-buffered in regs, 2 chunks (16 int4-pairs) in flight, next
//     chunk's loads interleaved one pair per K-step -> 16-32 outstanding.
//   - Spack 4-deep rotating prefetch (load ks+4 while consuming ks).
// 256 blocks x 4 waves = 1024 waves (1/SIMD) -> VGPR budget ~512, no spill.
// ---------------------------------------------------------------------------
__global__ __launch_bounds__(256, 1) void mega2_kernel(
    const int* __restrict__ questions, const int* __restrict__ T,
    const float* __restrict__ dfeat, const float* __restrict__ Qemb,
    const float* __restrict__ Wdiff, const float* __restrict__ bdiff,
    const float* __restrict__ Wfc, const float* __restrict__ bfc,
    const float* __restrict__ Wout, const float* __restrict__ bout,
    const unsigned short* __restrict__ Spack, const unsigned short* __restrict__ Wp,
    float* __restrict__ out_e, float* __restrict__ out_p)
{
    __shared__ alignas(16) unsigned short zb[4][16][200];  // per-wave z (192 used)
    __shared__ float cnt16[4][16];
    __shared__ float scal[4][16][3];

    const int tid  = threadIdx.x;
    const int lane = tid & 63;
    const int wid  = tid >> 6;
    const int g    = lane >> 4;
    const int rl   = lane & 15;
    const int wrow = (blockIdx.x * 4 + wid) * 16;          // this wave's 16 rows

    unsigned short (*z)[200] = zb[wid];
    float* cw = cnt16[wid];
    float (*sc)[3] = scal[wid];

    // ---- phase A: full-K T@S, deep-pipelined -------------------------------
    f32x4 a0{}, a1{}, a2{}, a3{};
    int c = 0;
    {
        const int* tp = T + (size_t)(wrow + rl) * 1024 + g * 8;
        const unsigned short* sp = Spack + lane * 8;

        int4 tA[16], tB[16];
        bf16x8 s0[4], s1[4], s2[4], s3[4];

#define TCHUNK(buf, kb)                                                     \
        _Pragma("unroll") for (int i = 0; i < 8; ++i) {                     \
            buf[2*i]   = *(const int4*)(tp + ((kb) + i) * 32);              \
            buf[2*i+1] = *(const int4*)(tp + ((kb) + i) * 32 + 4);          \
        }
#define TPAIR(buf, i, kn)                                                   \
        { buf[2*(i)]   = *(const int4*)(tp + ((kn) + (i)) * 32);            \
          buf[2*(i)+1] = *(const int4*)(tp + ((kn) + (i)) * 32 + 4); }
#define SLOAD(buf, ks)                                                      \
        _Pragma("unroll") for (int f = 0; f < 4; ++f)                       \
            buf[f] = *(const bf16x8*)(sp + (size_t)(ks) * 2048 + f * 512);
#define KBODY(tbuf, ii, sbuf, ks)                                           \
        { bf16x8 c0 = sbuf[0], c1 = sbuf[1], c2 = sbuf[2], c3 = sbuf[3];    \
          if ((ks) + 4 < 32) { SLOAD(sbuf, (ks) + 4); }                     \
          int4 u = tbuf[2*(ii)], v = tbuf[2*(ii)+1];                        \
          c += u.x+u.y+u.z+u.w+v.x+v.y+v.z+v.w;                             \
          bf16x8 af = mk_af(u, v);                                          \
          a0 = __builtin_amdgcn_mfma_f32_16x16x32_bf16(af, c0, a0, 0,0,0);  \
          a1 = __builtin_amdgcn_mfma_f32_16x16x32_bf16(af, c1, a1, 0,0,0);  \
          a2 = __builtin_amdgcn_mfma_f32_16x16x32_bf16(af, c2, a2, 0,0,0);  \
          a3 = __builtin_amdgcn_mfma_f32_16x16x32_bf16(af, c3, a3, 0,0,0); }
// consume 8 steps from tbuf at kb, interleaving next-next chunk loads into nbuf at kn
#define CHUNK8P(tbuf, kb, nbuf, kn)                                         \
        KBODY(tbuf,0,s0,(kb)+0) TPAIR(nbuf,0,kn)                            \
        KBODY(tbuf,1,s1,(kb)+1) TPAIR(nbuf,1,kn)                            \
        KBODY(tbuf,2,s2,(kb)+2) TPAIR(nbuf,2,kn)                            \
        KBODY(tbuf,3,s3,(kb)+3) TPAIR(nbuf,3,kn)                            \
        KBODY(tbuf,4,s0,(kb)+4) TPAIR(nbuf,4,kn)                            \
        KBODY(tbuf,5,s1,(kb)+5) TPAIR(nbuf,5,kn)                            \
        KBODY(tbuf,6,s2,(kb)+6) TPAIR(nbuf,6,kn)                            \
        KBODY(tbuf,7,s3,(kb)+7) TPAIR(nbuf,7,kn)
#define CHUNK8(tbuf, kb)                                                    \
        KBODY(tbuf,0,s0,(kb)+0) KBODY(tbuf,1,s1,(kb)+1)                     \
        KBODY(tbuf,2,s2,(kb)+2) KBODY(tbuf,3,s3,(kb)+3)                     \
        KBODY(tbuf,4,s0,(kb)+4) KBODY(tbuf,5,s1,(kb)+5)                     \
        KBODY(tbuf,6,s2,(kb)+6) KBODY(tbuf,7,s3,(kb)+7)

        TCHUNK(tA, 0);                 // chunk 0 in flight
        SLOAD(s0, 0); SLOAD(s1, 1); SLOAD(s2, 2); SLOAD(s3, 3);
        TCHUNK(tB, 8);                 // chunk 1 in flight
        CHUNK8P(tA, 0,  tA, 16);       // consume 0..7,   load chunk 2
        CHUNK8P(tB, 8,  tB, 24);       // consume 8..15,  load chunk 3
        CHUNK8(tA, 16);                // consume 16..23
        CHUNK8(tB, 24);                // consume 24..31
#undef TCHUNK
#undef TPAIR
#undef SLOAD
#undef KBODY
#undef CHUNK8P
#undef CHUNK8
    }
    // counts: lane (g,rl) holds row rl partial; reduce over g
    c += __shfl_xor(c, 16);
    c += __shfl_xor(c, 32);
    if (lane < 16) cw[lane] = (float)c;

    // mu -> LDS (bf16). D layout: col = lane&15, row = (lane>>4)*4 + r
    {
        float inv[4];
#pragma unroll
        for (int r = 0; r < 4; ++r) inv[r] = 1.f / cw[g * 4 + r];
#pragma unroll
        for (int r = 0; r < 4; ++r) {
            int row = g * 4 + r;
            z[row][64 + rl]      = f2bf(a0[r] * inv[r]);
            z[row][64 + 16 + rl] = f2bf(a1[r] * inv[r]);
            z[row][64 + 32 + rl] = f2bf(a2[r] * inv[r]);
            z[row][64 + 48 + rl] = f2bf(a3[r] * inv[r]);
        }
    }

    // ---- phase B: q, a, dots; finish z (R8-verified) ------------------------
    {
        int r = lane >> 2, q4l = lane & 3, d0 = q4l * 16;   // 4 lanes per row
        int row = wrow + r;
        int qi = questions[row];

        float q[16], aa[16], mu[16];
#pragma unroll
        for (int b = 0; b < 4; ++b) {
            float4 v = *(const float4*)(Qemb + (size_t)qi * 64 + d0 + b * 4);
            q[b * 4 + 0] = v.x; q[b * 4 + 1] = v.y; q[b * 4 + 2] = v.z; q[b * 4 + 3] = v.w;
        }
        float f0 = dfeat[row * 3 + 0];
        float f1 = dfeat[row * 3 + 1];
        float f2 = dfeat[row * 3 + 2];
#pragma unroll
        for (int b = 0; b < 4; ++b) {
            float4 w0 = *(const float4*)(Wdiff + d0 + b * 4);
            float4 w1 = *(const float4*)(Wdiff + 64 + d0 + b * 4);
            float4 w2 = *(const float4*)(Wdiff + 128 + d0 + b * 4);
            float4 bd = *(const float4*)(bdiff + d0 + b * 4);
            aa[b * 4 + 0] = bd.x + f0 * w0.x + f1 * w1.x + f2 * w2.x;
            aa[b * 4 + 1] = bd.y + f0 * w0.y + f1 * w1.y + f2 * w2.y;
            aa[b * 4 + 2] = bd.z + f0 * w0.z + f1 * w1.z + f2 * w2.z;
            aa[b * 4 + 3] = bd.w + f0 * w0.w + f1 * w1.w + f2 * w2.w;
        }
#pragma unroll
        for (int b = 0; b < 2; ++b) {
            ushort4 m0 = *(const ushort4*)&z[r][64 + d0 + b * 8];
            ushort4 m1 = *(const ushort4*)&z[r][64 + d0 + b * 8 + 4];
            mu[b * 8 + 0] = bf2f(m0.x); mu[b * 8 + 1] = bf2f(m0.y);
            mu[b * 8 + 2] = bf2f(m0.z); mu[b * 8 + 3] = bf2f(m0.w);
            mu[b * 8 + 4] = bf2f(m1.x); mu[b * 8 + 5] = bf2f(m1.y);
            mu[b * 8 + 6] = bf2f(m1.z); mu[b * 8 + 7] = bf2f(m1.w);
        }
        float s12 = 0.f, s13 = 0.f, s23 = 0.f;
#pragma unroll
        for (int d = 0; d < 16; ++d) {
            s12 += q[d] * mu[d];
            s13 += q[d] * aa[d];
            s23 += mu[d] * aa[d];
        }
        s12 += __shfl_xor(s12, 1); s12 += __shfl_xor(s12, 2);
        s13 += __shfl_xor(s13, 1); s13 += __shfl_xor(s13, 2);
        s23 += __shfl_xor(s23, 1); s23 += __shfl_xor(s23, 2);
        if (q4l == 0) { sc[r][0] = s12; sc[r][1] = s13; sc[r][2] = s23; }

        ushort4 v;
#pragma unroll
        for (int b = 0; b < 4; ++b) {
            v.x = f2bf(q[b * 4 + 0]); v.y = f2bf(q[b * 4 + 1]);
            v.z = f2bf(q[b * 4 + 2]); v.w = f2bf(q[b * 4 + 3]);
            *(ushort4*)&z[r][d0 + b * 4] = v;
        }
#pragma unroll
        for (int b = 0; b < 4; ++b) {
            v.x = f2bf(aa[b * 4 + 0]); v.y = f2bf(aa[b * 4 + 1]);
            v.z = f2bf(aa[b * 4 + 2]); v.w = f2bf(aa[b * 4 + 3]);
            *(ushort4*)&z[r][128 + d0 + b * 4] = v;
        }
    }

    // ---- phase C: tail GEMM (K=192, 8 col-tiles) + epilogue (R8-verified) ---
    {
        bf16x8 afr[6];
#pragma unroll
        for (int kt = 0; kt < 6; ++kt)
            afr[kt] = *(const bf16x8*)&z[rl][kt * 32 + g * 8];

        float s0_ = sc[g * 4 + 0][0], s1_ = sc[g * 4 + 0][1], s2_ = sc[g * 4 + 0][2];
        float t0_ = sc[g * 4 + 1][0], t1_ = sc[g * 4 + 1][1], t2_ = sc[g * 4 + 1][2];
        float u0_ = sc[g * 4 + 2][0], u1_ = sc[g * 4 + 2][1], u2_ = sc[g * 4 + 2][2];
        float v0_ = sc[g * 4 + 3][0], v1_ = sc[g * 4 + 3][1], v2_ = sc[g * 4 + 3][2];

        float pr0 = 0.f, pr1 = 0.f, pr2 = 0.f, pr3 = 0.f;
#pragma unroll
        for (int ct = 0; ct < 8; ++ct) {
            f32x4 e{};
            const unsigned short* wp = Wp + (size_t)ct * 512 + lane * 8;
#pragma unroll
            for (int kt = 0; kt < 6; ++kt) {
                bf16x8 bfr = *(const bf16x8*)(wp + (size_t)kt * 4096);
                e = __builtin_amdgcn_mfma_f32_16x16x32_bf16(afr[kt], bfr, e, 0, 0, 0);
            }
            int h = ct * 16 + rl;
            float w192 = Wfc[192 * 128 + h];
            float w193 = Wfc[193 * 128 + h];
            float w194 = Wfc[194 * 128 + h];
            float bb = bfc[h];
            float wo = Wout[h];

            float ev;
            ev = e[0] + bb + s0_ * w192 + s1_ * w193 + s2_ * w194;
            ev = ev > 0.f ? ev : 0.f;
            out_e[(size_t)(wrow + g * 4 + 0) * 128 + h] = ev;  pr0 += ev * wo;
            ev = e[1] + bb + t0_ * w192 + t1_ * w193 + t2_ * w194;
            ev = ev > 0.f ? ev : 0.f;
            out_e[(size_t)(wrow + g * 4 + 1) * 128 + h] = ev;  pr1 += ev * wo;
            ev = e[2] + bb + u0_ * w192 + u1_ * w193 + u2_ * w194;
            ev = ev > 0.f ? ev : 0.f;
            out_e[(size_t)(wrow + g * 4 + 2) * 128 + h] = ev;  pr2 += ev * wo;
            ev = e[3] + bb + v0_ * w192 + v1_ * w193 + v2_ * w194;
            ev = ev > 0.f ? ev : 0.f;
            out_e[(size_t)(wrow + g * 4 + 3) * 128 + h] = ev;  pr3 += ev * wo;
        }
#pragma unroll
        for (int off = 1; off < 16; off <<= 1) {
            pr0 += __shfl_xor(pr0, off);
            pr1 += __shfl_xor(pr1, off);
            pr2 += __shfl_xor(pr2, off);
            pr3 += __shfl_xor(pr3, off);
        }
        if (rl == 0) {
            float bo = bout[0];
            out_p[wrow + g * 4 + 0] = 1.f / (1.f + expf(-(pr0 + bo)));
            out_p[wrow + g * 4 + 1] = 1.f / (1.f + expf(-(pr1 + bo)));
            out_p[wrow + g * 4 + 2] = 1.f / (1.f + expf(-(pr2 + bo)));
            out_p[wrow + g * 4 + 3] = 1.f / (1.f + expf(-(pr3 + bo)));
        }
    }
}

// ---------------------------------------------------------------------------
extern "C" void kernel_launch(void* const* d_in, const int* in_sizes, int n_in,
                              void* d_out, int out_size, void* d_ws, size_t ws_size,
                              hipStream_t stream)
{
    const int*   questions = (const int*)d_in[0];
    const int*   T         = (const int*)d_in[1];
    const float* dfeat     = (const float*)d_in[2];
    const float* Qemb      = (const float*)d_in[3];
    const float* Semb      = (const float*)d_in[4];
    const float* Wdiff     = (const float*)d_in[5];
    const float* bdiff     = (const float*)d_in[6];
    const float* Wfc       = (const float*)d_in[7];
    const float* bfc       = (const float*)d_in[8];
    const float* Wout      = (const float*)d_in[9];
    const float* bout      = (const float*)d_in[10];

    char* ws = (char*)d_ws;
    unsigned short* Spack = (unsigned short*)ws;             // 128 KiB
    unsigned short* Wp    = (unsigned short*)(ws + 131072);  // 48 KiB

    float* out_e = (float*)d_out;
    float* out_p = out_e + (size_t)BATCH * HID;

    hipLaunchKernelGGL(prep_pack, dim3(352), dim3(256), 0, stream, Semb, Wfc, Spack, Wp);
    hipLaunchKernelGGL(mega2_kernel, dim3(BATCH / 64), dim3(256), 0, stream,
                       questions, T, dfeat, Qemb, Wdiff, bdiff, Wfc, bfc, Wout, bout,
                       Spack, Wp, out_e, out_p);
}

// Round 17
// 27.995 us; speedup vs baseline: 2.0197x; 1.1549x over previous
//
#include <hip/hip_runtime.h>
#include <hip/hip_bf16.h>

#define BATCH   16384
#define NTAGS   1024
#define DIM     64
#define HID     128

typedef __attribute__((ext_vector_type(8))) short bf16x8;
typedef __attribute__((ext_vector_type(4))) float f32x4;

__device__ __forceinline__ unsigned short f2bf(float v) {
    unsigned u = __builtin_bit_cast(unsigned, v);
    return (unsigned short)((u + 0x7FFFu + ((u >> 16) & 1u)) >> 16);   // RNE
}

// ---------------------------------------------------------------------------
// prep, coalesced-read version: linear reads of S_emb / Wfc, scattered 2B
// writes into the bf16 16x16x32 B-frag layouts (col = lane&15, k = (lane>>4)*8+j).
// Spack: [ks(32)][nf(4)][l(64)][j(8)];  Wp: [kt(6)][ct(8)][l(64)][j(8)]
// ---------------------------------------------------------------------------
__global__ __launch_bounds__(256) void prep_pack(const float* __restrict__ S,
                                                 const float* __restrict__ Wfc,
                                                 unsigned short* __restrict__ Spack,
                                                 unsigned short* __restrict__ Wp)
{
    int tid = blockIdx.x * 256 + threadIdx.x;   // 0..90111
    if (tid < 65536) {
        int k = tid >> 6, d = tid & 63;          // S[k][d], coalesced read
        float v = S[tid];
        int ks = k >> 5, rem = k & 31, lhi = rem >> 3, j = rem & 7;
        int nf = d >> 4, rl = d & 15, l = lhi * 16 + rl;
        Spack[((size_t)(ks * 4 + nf) * 64 + l) * 8 + j] = f2bf(v);
    } else if (tid < 65536 + 24576) {
        int t2 = tid - 65536;                    // Wfc[k][col], coalesced read
        int k = t2 >> 7, col = t2 & 127;
        float v = Wfc[t2];
        int kt = k >> 5, rem = k & 31, lhi = rem >> 3, j = rem & 7;
        int ct = col >> 4, rl = col & 15, l = lhi * 16 + rl;
        Wp[((size_t)(kt * 8 + ct) * 64 + l) * 8 + j] = f2bf(v);
    }
}

// ---------------------------------------------------------------------------
// fused (R12 = session best, 28.0 us): R3 phase structure, int-add counts,
// tail-operand prefetch. Decomposition (R11/R15 REP-measured):
//   phase 1 ~14 us (T 64MB from L3 + Spack 128MB from L2, BW floor)
//   tail    ~5.5 us (phases 2-3 + barriers)
//   fixed   ~4.5 us (launch/ramp)
// ---------------------------------------------------------------------------
__global__ __launch_bounds__(256, 3) void fused_kernel(
    const int* __restrict__ questions, const int* __restrict__ T,
    const float* __restrict__ dfeat, const float* __restrict__ Qemb,
    const float* __restrict__ Wdiff, const float* __restrict__ bdiff,
    const float* __restrict__ Wfc, const float* __restrict__ bfc,
    const float* __restrict__ Wout, const float* __restrict__ bout,
    const unsigned short* __restrict__ Spack, const unsigned short* __restrict__ Wp,
    float* __restrict__ out_e, float* __restrict__ out_p)
{
    __shared__ alignas(16) float accred[4][16][68];
    __shared__ float cntred[4][16];
    __shared__ alignas(16) unsigned short zb[16][200];
    __shared__ float scal[16][3];
    __shared__ float pacc[16][4];

    const int tid  = threadIdx.x;
    const int lane = tid & 63;
    const int wid  = tid >> 6;
    const int g    = lane >> 4;
    const int rl   = lane & 15;
    const int rb   = blockIdx.x * 16;

    // ---- prefetch tail operands --------------------------------------------
    const int pr_r = tid >> 4, pr_c = tid & 15, pr_d0 = pr_c * 4;
    const int qi = questions[rb + pr_r];
    const float4 q4 = *(const float4*)(Qemb + (size_t)qi * 64 + pr_d0);
    const float pf0 = dfeat[(rb + pr_r) * 3 + 0];
    const float pf1 = dfeat[(rb + pr_r) * 3 + 1];
    const float pf2 = dfeat[(rb + pr_r) * 3 + 2];

    bf16x8 wpf[12];
    float w192v[2], w193v[2], w194v[2], bbv[2], wov[2];
#pragma unroll
    for (int c2 = 0; c2 < 2; ++c2) {
        int ct = wid * 2 + c2;
        const unsigned short* wpb = Wp + (size_t)ct * 512 + lane * 8;
#pragma unroll
        for (int kt = 0; kt < 6; ++kt)
            wpf[c2 * 6 + kt] = *(const bf16x8*)(wpb + (size_t)kt * 4096);
        int h = ct * 16 + rl;
        w192v[c2] = Wfc[192 * 128 + h];
        w193v[c2] = Wfc[193 * 128 + h];
        w194v[c2] = Wfc[194 * 128 + h];
        bbv[c2]   = bfc[h];
        wov[c2]   = Wout[h];
    }

    // ---- phase 1: T @ S over this wave's K-quarter --------------------------
    f32x4 a0{}, a1{}, a2{}, a3{};
    int c = 0;
    {
        const int* tp = T + (size_t)(rb + rl) * 1024 + wid * 256 + g * 8;
        const unsigned short* sp = Spack + (size_t)wid * 8 * 2048 + lane * 8;

#pragma unroll
        for (int ks = 0; ks < 8; ++ks) {
            int4 t0 = *(const int4*)(tp + ks * 32);
            int4 t1 = *(const int4*)(tp + ks * 32 + 4);
            c += t0.x + t0.y + t0.z + t0.w + t1.x + t1.y + t1.z + t1.w;
            bf16x8 af;
            af[0] = (short)((-t0.x) & 0x3F80);
            af[1] = (short)((-t0.y) & 0x3F80);
            af[2] = (short)((-t0.z) & 0x3F80);
            af[3] = (short)((-t0.w) & 0x3F80);
            af[4] = (short)((-t1.x) & 0x3F80);
            af[5] = (short)((-t1.y) & 0x3F80);
            af[6] = (short)((-t1.z) & 0x3F80);
            af[7] = (short)((-t1.w) & 0x3F80);

            const unsigned short* s2 = sp + ks * 2048;
            bf16x8 b0 = *(const bf16x8*)(s2);
            bf16x8 b1 = *(const bf16x8*)(s2 + 512);
            bf16x8 b2 = *(const bf16x8*)(s2 + 1024);
            bf16x8 b3 = *(const bf16x8*)(s2 + 1536);

            a0 = __builtin_amdgcn_mfma_f32_16x16x32_bf16(af, b0, a0, 0, 0, 0);
            a1 = __builtin_amdgcn_mfma_f32_16x16x32_bf16(af, b1, a1, 0, 0, 0);
            a2 = __builtin_amdgcn_mfma_f32_16x16x32_bf16(af, b2, a2, 0, 0, 0);
            a3 = __builtin_amdgcn_mfma_f32_16x16x32_bf16(af, b3, a3, 0, 0, 0);
        }
    }
    c += __shfl_xor(c, 16);
    c += __shfl_xor(c, 32);
    if (lane < 16) cntred[wid][lane] = (float)c;

    // D layout: col = lane&15, row = (lane>>4)*4 + r
#pragma unroll
    for (int r = 0; r < 4; ++r) {
        int row = g * 4 + r;
        accred[wid][row][rl]      = a0[r];
        accred[wid][row][16 + rl] = a1[r];
        accred[wid][row][32 + rl] = a2[r];
        accred[wid][row][48 + rl] = a3[r];
    }
    __syncthreads();

    // ---- phase 2: combine partials, build z (bf16) --------------------------
    {
        int r = pr_r, c16 = pr_c, d0 = pr_d0;
        float cc = cntred[0][r] + cntred[1][r] + cntred[2][r] + cntred[3][r];
        float inv = 1.f / cc;
        float4 m0 = *(const float4*)&accred[0][r][d0];
        float4 m1 = *(const float4*)&accred[1][r][d0];
        float4 m2 = *(const float4*)&accred[2][r][d0];
        float4 m3 = *(const float4*)&accred[3][r][d0];
        float mu[4];
        mu[0] = (m0.x + m1.x + m2.x + m3.x) * inv;
        mu[1] = (m0.y + m1.y + m2.y + m3.y) * inv;
        mu[2] = (m0.z + m1.z + m2.z + m3.z) * inv;
        mu[3] = (m0.w + m1.w + m2.w + m3.w) * inv;

        float q[4] = {q4.x, q4.y, q4.z, q4.w};
        float aa[4];
#pragma unroll
        for (int d = 0; d < 4; ++d)
            aa[d] = bdiff[d0 + d] + pf0 * Wdiff[d0 + d] + pf1 * Wdiff[64 + d0 + d]
                  + pf2 * Wdiff[128 + d0 + d];

        ushort4 qv, mv, av;
        qv.x = f2bf(q[0]);  qv.y = f2bf(q[1]);  qv.z = f2bf(q[2]);  qv.w = f2bf(q[3]);
        mv.x = f2bf(mu[0]); mv.y = f2bf(mu[1]); mv.z = f2bf(mu[2]); mv.w = f2bf(mu[3]);
        av.x = f2bf(aa[0]); av.y = f2bf(aa[1]); av.z = f2bf(aa[2]); av.w = f2bf(aa[3]);
        *(ushort4*)&zb[r][d0]       = qv;
        *(ushort4*)&zb[r][64 + d0]  = mv;
        *(ushort4*)&zb[r][128 + d0] = av;

        float s12 = 0.f, s13 = 0.f, s23 = 0.f;
#pragma unroll
        for (int d = 0; d < 4; ++d) {
            s12 += q[d] * mu[d];
            s13 += q[d] * aa[d];
            s23 += mu[d] * aa[d];
        }
#pragma unroll
        for (int off = 1; off < 16; off <<= 1) {
            s12 += __shfl_xor(s12, off);
            s13 += __shfl_xor(s13, off);
            s23 += __shfl_xor(s23, off);
        }
        if (c16 == 0) { scal[r][0] = s12; scal[r][1] = s13; scal[r][2] = s23; }
    }
    __syncthreads();

    // ---- phase 3: tail GEMM (K=192) + epilogue (operands in registers) ------
    {
        bf16x8 afr[6];
#pragma unroll
        for (int kt = 0; kt < 6; ++kt)
            afr[kt] = *(const bf16x8*)&zb[rl][kt * 32 + g * 8];

        float pr0 = 0.f, pr1 = 0.f, pr2 = 0.f, pr3 = 0.f;
#pragma unroll
        for (int c2 = 0; c2 < 2; ++c2) {
            int ct = wid * 2 + c2;
            f32x4 e{};
#pragma unroll
            for (int kt = 0; kt < 6; ++kt)
                e = __builtin_amdgcn_mfma_f32_16x16x32_bf16(afr[kt], wpf[c2 * 6 + kt], e, 0, 0, 0);
            int h = ct * 16 + rl;
#pragma unroll
            for (int r = 0; r < 4; ++r) {
                int row = g * 4 + r;
                float ev = e[r] + bbv[c2] + scal[row][0] * w192v[c2]
                         + scal[row][1] * w193v[c2] + scal[row][2] * w194v[c2];
                ev = ev > 0.f ? ev : 0.f;
                out_e[(size_t)(rb + row) * 128 + h] = ev;
                float pc = ev * wov[c2];
                if (r == 0) pr0 += pc; else if (r == 1) pr1 += pc;
                else if (r == 2) pr2 += pc; else pr3 += pc;
            }
        }
#pragma unroll
        for (int off = 1; off < 16; off <<= 1) {
            pr0 += __shfl_xor(pr0, off);
            pr1 += __shfl_xor(pr1, off);
            pr2 += __shfl_xor(pr2, off);
            pr3 += __shfl_xor(pr3, off);
        }
        if (rl == 0) {
            pacc[g * 4 + 0][wid] = pr0;
            pacc[g * 4 + 1][wid] = pr1;
            pacc[g * 4 + 2][wid] = pr2;
            pacc[g * 4 + 3][wid] = pr3;
        }
    }
    __syncthreads();
    if (tid < 16) {
        float v = pacc[tid][0] + pacc[tid][1] + pacc[tid][2] + pacc[tid][3] + bout[0];
        out_p[rb + tid] = 1.f / (1.f + expf(-v));
    }
}

// ---------------------------------------------------------------------------
extern "C" void kernel_launch(void* const* d_in, const int* in_sizes, int n_in,
                              void* d_out, int out_size, void* d_ws, size_t ws_size,
                              hipStream_t stream)
{
    const int*   questions = (const int*)d_in[0];
    const int*   T         = (const int*)d_in[1];
    const float* dfeat     = (const float*)d_in[2];
    const float* Qemb      = (const float*)d_in[3];
    const float* Semb      = (const float*)d_in[4];
    const float* Wdiff     = (const float*)d_in[5];
    const float* bdiff     = (const float*)d_in[6];
    const float* Wfc       = (const float*)d_in[7];
    const float* bfc       = (const float*)d_in[8];
    const float* Wout      = (const float*)d_in[9];
    const float* bout      = (const float*)d_in[10];

    char* ws = (char*)d_ws;
    unsigned short* Spack = (unsigned short*)ws;             // 128 KiB
    unsigned short* Wp    = (unsigned short*)(ws + 131072);  // 48 KiB

    float* out_e = (float*)d_out;
    float* out_p = out_e + (size_t)BATCH * HID;

    hipLaunchKernelGGL(prep_pack, dim3(352), dim3(256), 0, stream, Semb, Wfc, Spack, Wp);
    hipLaunchKernelGGL(fused_kernel, dim3(BATCH / 16), dim3(256), 0, stream,
                       questions, T, dfeat, Qemb, Wdiff, bdiff, Wfc, bfc, Wout, bout,
                       Spack, Wp, out_e, out_p);
}